// Round 5
// baseline (187.370 us; speedup 1.0000x reference)
//
#include <hip/hip_runtime.h>

// TrainableHedgehog forward as chunk-parallel linear attention, full-MFMA edition.
// q,k,v: [2,16,2048,64] fp32; Wq,Wk: [4,16,64,64] fp32; out fp32.
// All GEMM-shaped work on v_mfma_f32_16x16x32_bf16 with hi/lo bf16 x3-product
// splitting (~fp32 accuracy). S carried through workspace as bf16 hi/lo planes.
#define BH_N   32
#define H_N    16
#define L_N    2048
#define D_N    64
#define F_N    64
#define FF_N   128
#define CH_N   64
#define NC_N   32
#define EPSF   1e-12f

#define S_STRIDE (D_N*FF_N)                 // 8192 elems per (bh,chunk), layout [d][2F]
#define SH_TOTAL ((size_t)BH_N*NC_N*S_STRIDE)   // u16 elems per plane
#define Z_TOTAL  ((size_t)BH_N*NC_N*FF_N)
#define WT_HEAD  (F_N*D_N)                  // 4096 elements per head
#define WT_MAT   (H_N*WT_HEAD)              // 65536 per (matrix, hi/lo half)

typedef unsigned short u16;
typedef unsigned int   u32;
typedef short bf16x8 __attribute__((ext_vector_type(8)));
typedef float f32x4  __attribute__((ext_vector_type(4)));

#define MFMA16(A,B,C) __builtin_amdgcn_mfma_f32_16x16x32_bf16(A,B,C,0,0,0)

// fp32 -> (hi, lo) bf16 pair: x ~= hi + lo with |err| <= 2^-16 |x|
__device__ __forceinline__ void split_hl(float x, u16& h, u16& l){
  unsigned u = __float_as_uint(x);
  h = (u16)(u >> 16);
  float hf = __uint_as_float(u & 0xffff0000u);
  l = (u16)(__float_as_uint(x - hf) >> 16);
}

// Swizzled tile indices (units = elements). XOR of row low bits into the
// 16B-slot bits makes MFMA fragment reads (16 rows, same col-range) conflict-free.
__device__ __forceinline__ int ix128(int r, int c){ return (r*128 + c) ^ ((r&7)<<3); } // bf16, 128 cols
__device__ __forceinline__ int ix64 (int r, int c){ return (r*64  + c) ^ ((r&7)<<3); } // bf16, 64 cols
__device__ __forceinline__ int ixA  (int r, int c){ return (r*64  + c) ^ ((r&7)<<2); } // fp32, 64 cols

__device__ __forceinline__ bf16x8 ldf128(const u16* t, int r, int k0){
  return *reinterpret_cast<const bf16x8*>(t + ix128(r,k0));
}
__device__ __forceinline__ bf16x8 ldf64(const u16* t, int r, int k0){
  return *reinterpret_cast<const bf16x8*>(t + ix64(r,k0));
}

__device__ __forceinline__ void cvt8(const float* __restrict__ p, bf16x8& h8, bf16x8& l8){
  f32x4 a = *reinterpret_cast<const f32x4*>(p);
  f32x4 b = *reinterpret_cast<const f32x4*>(p+4);
  float v[8] = {a[0],a[1],a[2],a[3],b[0],b[1],b[2],b[3]};
  #pragma unroll
  for (int i=0;i<8;++i){ u16 hh,ll; split_hl(v[i],hh,ll); h8[i]=(short)hh; l8[i]=(short)ll; }
}

// ---- phi einsum on MFMA: o[m0..m0+16][0..64] in C-layout -------------------
__device__ __forceinline__ void o_mfma(const float* __restrict__ X,
                                       const u16* __restrict__ WTh,
                                       const u16* __restrict__ WTl,
                                       int m0, int lane, f32x4 oacc[4])
{
  int lrow = lane&15, k0l = (lane>>4)*8;
  bf16x8 xh[2], xl[2];
  #pragma unroll
  for (int ks=0; ks<2; ++ks)
    cvt8(X + (size_t)(m0+lrow)*D_N + ks*32 + k0l, xh[ks], xl[ks]);
  #pragma unroll
  for (int ft=0; ft<4; ++ft) oacc[ft] = (f32x4){0.f,0.f,0.f,0.f};
  #pragma unroll
  for (int ks=0; ks<2; ++ks){
    #pragma unroll
    for (int ft=0; ft<4; ++ft){
      const u16* bp = WTh + (ft*16+lrow)*D_N + ks*32 + k0l;
      const u16* bq = WTl + (ft*16+lrow)*D_N + ks*32 + k0l;
      bf16x8 wh = *reinterpret_cast<const bf16x8*>(bp);
      bf16x8 wl = *reinterpret_cast<const bf16x8*>(bq);
      oacc[ft] = MFMA16(xh[ks], wh, oacc[ft]);
      oacc[ft] = MFMA16(xh[ks], wl, oacc[ft]);
      oacc[ft] = MFMA16(xl[ks], wh, oacc[ft]);
    }
  }
}

// dual softmax over f (row-wise) in C-layout; 16-lane shuffle reductions.
__device__ __forceinline__ void softmax_cl(const f32x4 oacc[4], f32x4 pP[4], f32x4 pM[4])
{
  #pragma unroll
  for (int reg=0; reg<4; ++reg){
    float mP = fmaxf(fmaxf(oacc[0][reg],oacc[1][reg]), fmaxf(oacc[2][reg],oacc[3][reg]));
    float mM = fminf(fminf(oacc[0][reg],oacc[1][reg]), fminf(oacc[2][reg],oacc[3][reg]));
    #pragma unroll
    for (int o=8;o>0;o>>=1){ mP = fmaxf(mP,__shfl_xor(mP,o,64)); mM = fminf(mM,__shfl_xor(mM,o,64)); }
    float eP[4], eM[4], sP=0.f, sM=0.f;
    #pragma unroll
    for (int ft=0; ft<4; ++ft){
      eP[ft] = __expf(oacc[ft][reg]-mP);
      eM[ft] = __expf(mM-oacc[ft][reg]);
      sP += eP[ft]; sM += eM[ft];
    }
    #pragma unroll
    for (int o=8;o>0;o>>=1){ sP += __shfl_xor(sP,o,64); sM += __shfl_xor(sM,o,64); }
    float iP = 1.f/sP, iM = 1.f/sM;
    #pragma unroll
    for (int ft=0; ft<4; ++ft){
      pP[ft][reg] = fmaxf(eP[ft]*iP, EPSF);
      pM[ft][reg] = fmaxf(eM[ft]*iM, EPSF);
    }
  }
}

// store phi (C-layout regs) into swizzled LDS tile, row-major [m][128]
__device__ __forceinline__ void store_phi_rm(u16* th, u16* tl, int m0, int lane,
                                             const f32x4 pP[4], const f32x4 pM[4]){
  int lrow = lane&15, lkg = lane>>4;
  #pragma unroll
  for (int reg=0; reg<4; ++reg){
    int m = m0 + lkg*4 + reg;
    #pragma unroll
    for (int ft=0; ft<4; ++ft){
      int f = ft*16 + lrow;
      u16 hh,ll;
      split_hl(pP[ft][reg],hh,ll); th[ix128(m,f)]    = hh; tl[ix128(m,f)]    = ll;
      split_hl(pM[ft][reg],hh,ll); th[ix128(m,64+f)] = hh; tl[ix128(m,64+f)] = ll;
    }
  }
}

// store phi transposed [f][m] (for phase-1 B-frags of S = V^T . phik)
__device__ __forceinline__ void store_phi_tr(u16* th, u16* tl, int m0, int lane,
                                             const f32x4 pP[4], const f32x4 pM[4]){
  int lrow = lane&15, lkg = lane>>4;
  #pragma unroll
  for (int reg=0; reg<4; ++reg){
    int m = m0 + lkg*4 + reg;
    #pragma unroll
    for (int ft=0; ft<4; ++ft){
      int f = ft*16 + lrow;
      u16 hh,ll;
      split_hl(pP[ft][reg],hh,ll); th[ix64(f,m)]    = hh; tl[ix64(f,m)]    = ll;
      split_hl(pM[ft][reg],hh,ll); th[ix64(64+f,m)] = hh; tl[ix64(64+f,m)] = ll;
    }
  }
}

// ---------------- Phase 0: W transpose + hi/lo split (per launch, ~us) ------
__global__ __launch_bounds__(256)
void hh_wprep(const float* __restrict__ Wq, const float* __restrict__ Wk,
              const int* __restrict__ lidx, u16* __restrict__ WT)
{
  __shared__ float tile[64*65];
  int bid = blockIdx.x, which = bid & 1, h = bid >> 1;
  const float* Wsrc = (which ? Wk : Wq) + (size_t)(*lidx)*(H_N*D_N*F_N) + (size_t)h*(D_N*F_N);
  u16* dh = WT + which*(2*WT_MAT) + h*WT_HEAD;
  u16* dl = dh + WT_MAT;
  int t = threadIdx.x;
  #pragma unroll
  for (int i=0;i<16;++i){
    int idx = i*256 + t;                      // idx = d*64 + f
    tile[(idx&63)*65 + (idx>>6)] = Wsrc[idx]; // tile[f][d]
  }
  __syncthreads();
  #pragma unroll
  for (int i=0;i<16;++i){
    int idx = i*256 + t;                      // idx = f*64 + d
    float w = tile[(idx>>6)*65 + (idx&63)];
    u16 hh,ll; split_hl(w,hh,ll);
    dh[idx] = hh; dl[idx] = ll;
  }
}

// ---------------- Phase 1: per-chunk S_t = phi_k^T v (MFMA), z_t ------------
__global__ __launch_bounds__(256,3)
void hh_chunksums(const float* __restrict__ kin, const float* __restrict__ vin,
                  const u16* __restrict__ WkT,
                  u16* __restrict__ Sh_ws, u16* __restrict__ Sl_ws,
                  float* __restrict__ z_ws)
{
  __shared__ __align__(16) char sm[51200];
  u16*  pkT_h = (u16*)sm;               // [128 f][64 r] bf16 hi (16 KB)
  u16*  pkT_l = (u16*)(sm + 16384);
  u16*  vt_h  = (u16*)(sm + 32768);     // V^T [64 d][64 r] hi (8 KB)
  u16*  vt_l  = (u16*)(sm + 40960);
  float* zb   = (float*)(sm + 49152);   // [4][128] partial z (2 KB)

  int bid = blockIdx.x, bh = bid>>5, c = bid & (NC_N-1), h = bh & (H_N-1);
  const float* Xk = kin + ((size_t)bh*L_N + c*CH_N)*D_N;
  const float* Vc = vin + ((size_t)bh*L_N + c*CH_N)*D_N;
  const u16* Wh = WkT + h*WT_HEAD;
  const u16* Wl = Wh + WT_MAT;
  int t = threadIdx.x, lane = t&63, w = t>>6;

  // V loads early (coalesced)
  int vn = t>>2, vd0 = (t&3)*16;
  float4 vreg[4];
  #pragma unroll
  for (int p=0;p<4;++p)
    vreg[p] = *reinterpret_cast<const float4*>(Vc + (size_t)vn*D_N + vd0 + p*4);

  f32x4 oacc[4], pP[4], pM[4];
  o_mfma(Xk, Wh, Wl, w*16, lane, oacc);
  softmax_cl(oacc, pP, pM);
  store_phi_tr(pkT_h, pkT_l, w*16, lane, pP, pM);

  // z column sums (over this wave's 16 rows, then cross-lkg shuffle)
  #pragma unroll
  for (int ft=0; ft<4; ++ft){
    float sP = pP[ft][0]+pP[ft][1]+pP[ft][2]+pP[ft][3];
    float sM = pM[ft][0]+pM[ft][1]+pM[ft][2]+pM[ft][3];
    sP += __shfl_xor(sP,16,64); sP += __shfl_xor(sP,32,64);
    sM += __shfl_xor(sM,16,64); sM += __shfl_xor(sM,32,64);
    if ((lane>>4)==0){
      zb[w*128 + ft*16 + lane]      = sP;
      zb[w*128 + 64 + ft*16 + lane] = sM;
    }
  }

  // V^T staging
  #pragma unroll
  for (int p=0;p<4;++p){
    float vals[4] = {vreg[p].x, vreg[p].y, vreg[p].z, vreg[p].w};
    #pragma unroll
    for (int e=0;e<4;++e){
      int d = vd0 + p*4 + e;
      u16 hh,ll; split_hl(vals[e],hh,ll);
      vt_h[ix64(d, vn)] = hh;
      vt_l[ix64(d, vn)] = ll;
    }
  }
  __syncthreads();

  if (t < FF_N)
    z_ws[(size_t)(bh*NC_N + c)*FF_N + t] = zb[t] + zb[128+t] + zb[256+t] + zb[384+t];

  // S[d][f] = sum_r V^T[d][r] * phik[r][f]; wave w owns d-tile w.
  int m0 = w*16, lrow = lane&15, k0l = (lane>>4)*8;
  f32x4 acc[8];
  #pragma unroll
  for (int ft=0; ft<8; ++ft) acc[ft] = (f32x4){0.f,0.f,0.f,0.f};
  #pragma unroll
  for (int ks=0; ks<2; ++ks){
    int r0k = ks*32 + k0l;
    bf16x8 ah = ldf64(vt_h, m0 + lrow, r0k);
    bf16x8 al = ldf64(vt_l, m0 + lrow, r0k);
    #pragma unroll
    for (int ft=0; ft<8; ++ft){
      bf16x8 bh = ldf64(pkT_h, ft*16 + lrow, r0k);
      bf16x8 bl = ldf64(pkT_l, ft*16 + lrow, r0k);
      acc[ft] = MFMA16(ah, bh, acc[ft]);
      acc[ft] = MFMA16(ah, bl, acc[ft]);
      acc[ft] = MFMA16(al, bh, acc[ft]);
    }
  }
  // S out as bf16 hi/lo planes (aggregate per chunk; scan turns into prefix)
  u16* Shout = Sh_ws + (size_t)(bh*NC_N + c)*S_STRIDE;
  u16* Slout = Sl_ws + (size_t)(bh*NC_N + c)*S_STRIDE;
  #pragma unroll
  for (int ft=0; ft<8; ++ft)
    #pragma unroll
    for (int reg=0; reg<4; ++reg){
      int d = m0 + (lane>>4)*4 + reg;
      int idx = d*FF_N + ft*16 + lrow;
      u16 hh,ll; split_hl(acc[ft][reg],hh,ll);
      Shout[idx] = hh; Slout[idx] = ll;
    }
}

// ---------------- Phase 2: exclusive prefix scan over chunks (bf16 planes) --
__global__ __launch_bounds__(256)
void hh_scan(u16* __restrict__ Sh_ws, u16* __restrict__ Sl_ws,
             float* __restrict__ z_ws)
{
  int bid = blockIdx.x;
  int bh = bid / 17, s = bid % 17;
  int t = threadIdx.x;
  if (s < 16){
    // 2 elements per thread via paired u32 plane loads
    size_t base = (size_t)bh*NC_N*S_STRIDE + (size_t)s*512 + 2*t;
    float run0 = 0.f, run1 = 0.f;
    u32 nh = *reinterpret_cast<const u32*>(Sh_ws + base);
    u32 nl = *reinterpret_cast<const u32*>(Sl_ws + base);
    #pragma unroll
    for (int c=0; c<NC_N; ++c){
      u32 ch = nh, cl = nl;
      if (c+1 < NC_N){
        nh = *reinterpret_cast<const u32*>(Sh_ws + base + (size_t)(c+1)*S_STRIDE);
        nl = *reinterpret_cast<const u32*>(Sl_ws + base + (size_t)(c+1)*S_STRIDE);
      }
      // write exclusive prefix (run) over the aggregate slot
      u16 h0,l0,h1,l1; split_hl(run0,h0,l0); split_hl(run1,h1,l1);
      *reinterpret_cast<u32*>(Sh_ws + base + (size_t)c*S_STRIDE) = (u32)h0 | ((u32)h1<<16);
      *reinterpret_cast<u32*>(Sl_ws + base + (size_t)c*S_STRIDE) = (u32)l0 | ((u32)l1<<16);
      // accumulate reconstructed aggregate (hi+lo add is exact in fp32)
      run0 += __uint_as_float((ch & 0xffffu) << 16) + __uint_as_float((cl & 0xffffu) << 16);
      run1 += __uint_as_float(ch & 0xffff0000u)     + __uint_as_float(cl & 0xffff0000u);
    }
  } else if (t < FF_N){
    size_t base = (size_t)bh*NC_N*FF_N + t;
    float run = 0.f;
    float nxt = z_ws[base];
    #pragma unroll
    for (int c=0;c<NC_N;++c){
      float cur = nxt;
      if (c+1 < NC_N) nxt = z_ws[base + (size_t)(c+1)*FF_N];
      z_ws[base + (size_t)c*FF_N] = run;
      run += cur;
    }
  }
}

// ---------------- Phase 3: per-chunk output (everything on MFMA) ------------
__global__ __launch_bounds__(256,3)
void hh_output(const float* __restrict__ qin, const float* __restrict__ kin,
               const float* __restrict__ vin,
               const u16* __restrict__ WT,   // [WqT_h|WqT_l|WkT_h|WkT_l]
               const u16* __restrict__ Sh_ws, const u16* __restrict__ Sl_ws,
               const float* __restrict__ z_ws,
               float* __restrict__ out)
{
  __shared__ __align__(16) char sm[32768];
  u16*  ph   = (u16*)sm;                // phi tile hi [64][128] swz (16 KB)
  u16*  pl   = (u16*)(sm + 16384);      // lo
  float* aA  = (float*)sm;              // A [64][64] fp32 — aliases ph
  u16*  vt_h = (u16*)(sm + 16384);      // V^T — aliases pl
  u16*  vt_l = (u16*)(sm + 24576);

  int bid = blockIdx.x, bh = bid>>5, c = bid & (NC_N-1), h = bh & (H_N-1);
  const float* Xq = qin + ((size_t)bh*L_N + c*CH_N)*D_N;
  const float* Xk = kin + ((size_t)bh*L_N + c*CH_N)*D_N;
  const float* Vc = vin + ((size_t)bh*L_N + c*CH_N)*D_N;
  const u16* Sph = Sh_ws + (size_t)(bh*NC_N + c)*S_STRIDE; // excl prefix [d][2F] hi
  const u16* Spl = Sl_ws + (size_t)(bh*NC_N + c)*S_STRIDE; // lo
  const float* zp = z_ws + (size_t)(bh*NC_N + c)*FF_N;
  const u16* WqTh = WT + h*WT_HEAD;
  const u16* WqTl = WqTh + WT_MAT;
  const u16* WkTh = WT + 2*WT_MAT + h*WT_HEAD;
  const u16* WkTl = WkTh + WT_MAT;
  int t = threadIdx.x, lane = t&63, w = t>>6;
  int m0 = w*16, lrow = lane&15, lkg = lane>>4, k0l = lkg*8;

  // ---- phi_q: einsum (MFMA) + softmax + dz, through own-rows LDS to A-frags
  f32x4 oacc[4], pP[4], pM[4];
  o_mfma(Xq, WqTh, WqTl, m0, lane, oacc);
  softmax_cl(oacc, pP, pM);

  float dz[4];
  {
    float zqP[4], zqM[4];
    #pragma unroll
    for (int ft=0; ft<4; ++ft){
      zqP[ft] = zp[ft*16 + lrow];
      zqM[ft] = zp[64 + ft*16 + lrow];
    }
    #pragma unroll
    for (int reg=0; reg<4; ++reg){
      float s = 0.f;
      #pragma unroll
      for (int ft=0; ft<4; ++ft)
        s += pP[ft][reg]*zqP[ft] + pM[ft][reg]*zqM[ft];
      #pragma unroll
      for (int o=8;o>0;o>>=1) s += __shfl_xor(s,o,64);
      dz[reg] = s;
    }
  }

  store_phi_rm(ph, pl, m0, lane, pP, pM);
  // Each wave reads only its own 16 rows (which only it wrote) -> no barrier.
  bf16x8 qh[4], ql[4];
  #pragma unroll
  for (int ks=0; ks<4; ++ks){
    qh[ks] = ldf128(ph, m0 + lrow, ks*32 + k0l);
    ql[ks] = ldf128(pl, m0 + lrow, ks*32 + k0l);
  }

  // ---- inter numer = phiq . S_prefix^T FIRST: its global B-frag loads
  // (bf16 planes, no conversion) overlap the phi_k MFMA/softmax chain below.
  f32x4 accA[4], accO[4];
  #pragma unroll
  for (int i=0;i<4;++i){ accA[i]=(f32x4){0,0,0,0}; accO[i]=(f32x4){0,0,0,0}; }
  #pragma unroll
  for (int ks=0; ks<4; ++ks){
    int f0 = ks*32 + k0l;
    #pragma unroll
    for (int dt=0; dt<4; ++dt){
      bf16x8 sh = *reinterpret_cast<const bf16x8*>(Sph + (size_t)(dt*16 + lrow)*FF_N + f0);
      bf16x8 sl = *reinterpret_cast<const bf16x8*>(Spl + (size_t)(dt*16 + lrow)*FF_N + f0);
      accO[dt] = MFMA16(qh[ks], sh, accO[dt]);
      accO[dt] = MFMA16(qh[ks], sl, accO[dt]);
      accO[dt] = MFMA16(ql[ks], sh, accO[dt]);
    }
  }

  // ---- phi_k into the same tile (own rows again; no barrier needed yet)
  o_mfma(Xk, WkTh, WkTl, m0, lane, oacc);
  softmax_cl(oacc, pP, pM);
  store_phi_rm(ph, pl, m0, lane, pP, pM);

  // V loads (latency hidden under the MFMA section below)
  int vn = t>>2, vd0 = (t&3)*16;
  float4 vreg[4];
  #pragma unroll
  for (int p=0;p<4;++p)
    vreg[p] = *reinterpret_cast<const float4*>(Vc + (size_t)vn*D_N + vd0 + p*4);

  __syncthreads();  // all phi_k rows visible to all waves

  #pragma unroll
  for (int ks=0; ks<4; ++ks){
    int f0 = ks*32 + k0l;
    // intra A = phiq . phik^T (only ntiles <= w)
    #pragma unroll
    for (int nt=0; nt<4; ++nt){
      if (nt <= w){
        bf16x8 kh = ldf128(ph, nt*16 + lrow, f0);
        bf16x8 kl = ldf128(pl, nt*16 + lrow, f0);
        accA[nt] = MFMA16(qh[ks], kh, accA[nt]);
        accA[nt] = MFMA16(qh[ks], kl, accA[nt]);
        accA[nt] = MFMA16(ql[ks], kh, accA[nt]);
      }
    }
  }

  // causal mask own tile, row-sum for denominator
  float rs[4] = {0.f,0.f,0.f,0.f};
  #pragma unroll
  for (int nt=0; nt<4; ++nt)
    #pragma unroll
    for (int reg=0; reg<4; ++reg){
      float a = accA[nt][reg];
      if (nt > w) a = 0.f;
      if (nt == w && lrow > lkg*4 + reg) a = 0.f;  // keep n <= m
      accA[nt][reg] = a;
      rs[reg] += a;
    }
  float den[4];
  #pragma unroll
  for (int reg=0; reg<4; ++reg){
    float s = rs[reg];
    s += __shfl_xor(s,1,64); s += __shfl_xor(s,2,64);
    s += __shfl_xor(s,4,64); s += __shfl_xor(s,8,64);
    den[reg] = dz[reg] + s + EPSF;
  }

  __syncthreads();   // all waves done reading phik tile; safe to alias

  #pragma unroll
  for (int nt=0; nt<4; ++nt)
    #pragma unroll
    for (int reg=0; reg<4; ++reg){
      int m = m0 + lkg*4 + reg;
      aA[ixA(m, nt*16 + lrow)] = accA[nt][reg];
    }
  #pragma unroll
  for (int p=0;p<4;++p){
    float vals[4] = {vreg[p].x, vreg[p].y, vreg[p].z, vreg[p].w};
    #pragma unroll
    for (int e=0;e<4;++e){
      int d = vd0 + p*4 + e;
      u16 hh,ll; split_hl(vals[e],hh,ll);
      vt_h[ix64(d, vn)] = hh;
      vt_l[ix64(d, vn)] = ll;
    }
  }
  __syncthreads();

  // PV: accO += A . V   (waves 0,1 need 1 kstep; waves 2,3 need 2)
  #pragma unroll
  for (int ks=0; ks<2; ++ks){
    if (ks <= (w>>1)){
      int n0 = ks*32 + k0l;
      int m  = m0 + lrow;
      f32x4 a0 = *reinterpret_cast<const f32x4*>(aA + ixA(m, n0));
      f32x4 a1 = *reinterpret_cast<const f32x4*>(aA + ixA(m, n0+4));
      float av[8] = {a0[0],a0[1],a0[2],a0[3],a1[0],a1[1],a1[2],a1[3]};
      bf16x8 Ah, Al;
      #pragma unroll
      for (int i=0;i<8;++i){ u16 hh,ll; split_hl(av[i],hh,ll); Ah[i]=(short)hh; Al[i]=(short)ll; }
      #pragma unroll
      for (int dt=0; dt<4; ++dt){
        bf16x8 vh = ldf64(vt_h, dt*16 + lrow, n0);
        bf16x8 vl = ldf64(vt_l, dt*16 + lrow, n0);
        accO[dt] = MFMA16(Ah, vh, accO[dt]);
        accO[dt] = MFMA16(Ah, vl, accO[dt]);
        accO[dt] = MFMA16(Al, vh, accO[dt]);
      }
    }
  }

  #pragma unroll
  for (int reg=0; reg<4; ++reg){
    float inv = 1.0f / den[reg];
    int m = m0 + lkg*4 + reg;
    float* orow = out + ((size_t)bh*L_N + c*CH_N + m)*D_N;
    #pragma unroll
    for (int dt=0; dt<4; ++dt)
      orow[dt*16 + lrow] = accO[dt][reg] * inv;
  }
}

extern "C" void kernel_launch(void* const* d_in, const int* in_sizes, int n_in,
                              void* d_out, int out_size, void* d_ws, size_t ws_size,
                              hipStream_t stream) {
  const float* q    = (const float*)d_in[0];
  const float* k    = (const float*)d_in[1];
  const float* v    = (const float*)d_in[2];
  const float* Wq   = (const float*)d_in[3];
  const float* Wk   = (const float*)d_in[4];
  const int*   lidx = (const int*)d_in[5];
  float* out  = (float*)d_out;
  u16*   Sh_ws = (u16*)d_ws;                          // 16.78 MB
  u16*   Sl_ws = Sh_ws + SH_TOTAL;                    // 16.78 MB
  float* z_ws  = (float*)(Sl_ws + SH_TOTAL);          // 0.52 MB
  u16*   WT    = (u16*)(z_ws + Z_TOTAL);              // 0.5 MB

  hh_wprep    <<<2*H_N,     256, 0, stream>>>(Wq, Wk, lidx, WT);
  hh_chunksums<<<BH_N*NC_N, 256, 0, stream>>>(k, v, WT + 2*WT_MAT, Sh_ws, Sl_ws, z_ws);
  hh_scan     <<<BH_N*17,   256, 0, stream>>>(Sh_ws, Sl_ws, z_ws);
  hh_output   <<<BH_N*NC_N, 256, 0, stream>>>(q, k, v, WT, Sh_ws, Sl_ws, z_ws, out);
}

// Round 6
// 159.692 us; speedup vs baseline: 1.1733x; 1.1733x over previous
//
#include <hip/hip_runtime.h>

// TrainableHedgehog forward as chunk-parallel linear attention, full-MFMA edition.
// q,k,v: [2,16,2048,64] fp32; Wq,Wk: [4,16,64,64] fp32; out fp32.
// All GEMM-shaped work on v_mfma_f32_16x16x32_bf16 with hi/lo bf16 x3-product
// splitting (~fp32 accuracy). S carried through workspace as bf16 hi/lo planes.
#define BH_N   32
#define H_N    16
#define L_N    2048
#define D_N    64
#define F_N    64
#define FF_N   128
#define CH_N   64
#define NC_N   32
#define EPSF   1e-12f

#define S_STRIDE (D_N*FF_N)                 // 8192 elems per (bh,chunk), layout [d][2F]
#define SH_TOTAL ((size_t)BH_N*NC_N*S_STRIDE)   // u16 elems per plane
#define Z_TOTAL  ((size_t)BH_N*NC_N*FF_N)
#define WT_HEAD  (F_N*D_N)                  // 4096 elements per head
#define WT_MAT   (H_N*WT_HEAD)              // 65536 per (matrix, hi/lo half)

typedef unsigned short u16;
typedef unsigned int   u32;
typedef short bf16x8 __attribute__((ext_vector_type(8)));
typedef float f32x4  __attribute__((ext_vector_type(4)));

#define MFMA16(A,B,C) __builtin_amdgcn_mfma_f32_16x16x32_bf16(A,B,C,0,0,0)

// fp32 -> (hi, lo) bf16 pair: x ~= hi + lo with |err| <= 2^-16 |x|
__device__ __forceinline__ void split_hl(float x, u16& h, u16& l){
  unsigned u = __float_as_uint(x);
  h = (u16)(u >> 16);
  float hf = __uint_as_float(u & 0xffff0000u);
  l = (u16)(__float_as_uint(x - hf) >> 16);
}

// Swizzled tile indices (units = elements). XOR of row low bits into the
// 16B-slot bits makes MFMA fragment reads (16 rows, same col-range) conflict-free.
__device__ __forceinline__ int ix128(int r, int c){ return (r*128 + c) ^ ((r&7)<<3); } // bf16, 128 cols
__device__ __forceinline__ int ix64 (int r, int c){ return (r*64  + c) ^ ((r&7)<<3); } // bf16, 64 cols
__device__ __forceinline__ int ixA  (int r, int c){ return (r*64  + c) ^ ((r&7)<<2); } // fp32, 64 cols

__device__ __forceinline__ bf16x8 ldf128(const u16* t, int r, int k0){
  return *reinterpret_cast<const bf16x8*>(t + ix128(r,k0));
}
__device__ __forceinline__ bf16x8 ldf64(const u16* t, int r, int k0){
  return *reinterpret_cast<const bf16x8*>(t + ix64(r,k0));
}

__device__ __forceinline__ void cvt8(const float* __restrict__ p, bf16x8& h8, bf16x8& l8){
  f32x4 a = *reinterpret_cast<const f32x4*>(p);
  f32x4 b = *reinterpret_cast<const f32x4*>(p+4);
  float v[8] = {a[0],a[1],a[2],a[3],b[0],b[1],b[2],b[3]};
  #pragma unroll
  for (int i=0;i<8;++i){ u16 hh,ll; split_hl(v[i],hh,ll); h8[i]=(short)hh; l8[i]=(short)ll; }
}

// ---- phi einsum on MFMA: o[m0..m0+16][0..64] in C-layout -------------------
__device__ __forceinline__ void o_mfma(const float* __restrict__ X,
                                       const u16* __restrict__ WTh,
                                       const u16* __restrict__ WTl,
                                       int m0, int lane, f32x4 oacc[4])
{
  int lrow = lane&15, k0l = (lane>>4)*8;
  bf16x8 xh[2], xl[2];
  #pragma unroll
  for (int ks=0; ks<2; ++ks)
    cvt8(X + (size_t)(m0+lrow)*D_N + ks*32 + k0l, xh[ks], xl[ks]);
  #pragma unroll
  for (int ft=0; ft<4; ++ft) oacc[ft] = (f32x4){0.f,0.f,0.f,0.f};
  #pragma unroll
  for (int ks=0; ks<2; ++ks){
    #pragma unroll
    for (int ft=0; ft<4; ++ft){
      const u16* bp = WTh + (ft*16+lrow)*D_N + ks*32 + k0l;
      const u16* bq = WTl + (ft*16+lrow)*D_N + ks*32 + k0l;
      bf16x8 wh = *reinterpret_cast<const bf16x8*>(bp);
      bf16x8 wl = *reinterpret_cast<const bf16x8*>(bq);
      oacc[ft] = MFMA16(xh[ks], wh, oacc[ft]);
      oacc[ft] = MFMA16(xh[ks], wl, oacc[ft]);
      oacc[ft] = MFMA16(xl[ks], wh, oacc[ft]);
    }
  }
}

// dual softmax over f (row-wise) in C-layout; 16-lane shuffle reductions.
__device__ __forceinline__ void softmax_cl(const f32x4 oacc[4], f32x4 pP[4], f32x4 pM[4])
{
  #pragma unroll
  for (int reg=0; reg<4; ++reg){
    float mP = fmaxf(fmaxf(oacc[0][reg],oacc[1][reg]), fmaxf(oacc[2][reg],oacc[3][reg]));
    float mM = fminf(fminf(oacc[0][reg],oacc[1][reg]), fminf(oacc[2][reg],oacc[3][reg]));
    #pragma unroll
    for (int o=8;o>0;o>>=1){ mP = fmaxf(mP,__shfl_xor(mP,o,64)); mM = fminf(mM,__shfl_xor(mM,o,64)); }
    float eP[4], eM[4], sP=0.f, sM=0.f;
    #pragma unroll
    for (int ft=0; ft<4; ++ft){
      eP[ft] = __expf(oacc[ft][reg]-mP);
      eM[ft] = __expf(mM-oacc[ft][reg]);
      sP += eP[ft]; sM += eM[ft];
    }
    #pragma unroll
    for (int o=8;o>0;o>>=1){ sP += __shfl_xor(sP,o,64); sM += __shfl_xor(sM,o,64); }
    float iP = 1.f/sP, iM = 1.f/sM;
    #pragma unroll
    for (int ft=0; ft<4; ++ft){
      pP[ft][reg] = fmaxf(eP[ft]*iP, EPSF);
      pM[ft][reg] = fmaxf(eM[ft]*iM, EPSF);
    }
  }
}

// store phi (C-layout regs) into swizzled LDS tile, row-major [m][128]
__device__ __forceinline__ void store_phi_rm(u16* th, u16* tl, int m0, int lane,
                                             const f32x4 pP[4], const f32x4 pM[4]){
  int lrow = lane&15, lkg = lane>>4;
  #pragma unroll
  for (int reg=0; reg<4; ++reg){
    int m = m0 + lkg*4 + reg;
    #pragma unroll
    for (int ft=0; ft<4; ++ft){
      int f = ft*16 + lrow;
      u16 hh,ll;
      split_hl(pP[ft][reg],hh,ll); th[ix128(m,f)]    = hh; tl[ix128(m,f)]    = ll;
      split_hl(pM[ft][reg],hh,ll); th[ix128(m,64+f)] = hh; tl[ix128(m,64+f)] = ll;
    }
  }
}

// store phi transposed [f][m] (for phase-1 B-frags of S = V^T . phik)
__device__ __forceinline__ void store_phi_tr(u16* th, u16* tl, int m0, int lane,
                                             const f32x4 pP[4], const f32x4 pM[4]){
  int lrow = lane&15, lkg = lane>>4;
  #pragma unroll
  for (int reg=0; reg<4; ++reg){
    int m = m0 + lkg*4 + reg;
    #pragma unroll
    for (int ft=0; ft<4; ++ft){
      int f = ft*16 + lrow;
      u16 hh,ll;
      split_hl(pP[ft][reg],hh,ll); th[ix64(f,m)]    = hh; tl[ix64(f,m)]    = ll;
      split_hl(pM[ft][reg],hh,ll); th[ix64(64+f,m)] = hh; tl[ix64(64+f,m)] = ll;
    }
  }
}

// ---------------- Phase 0: W transpose + hi/lo split (per launch, ~us) ------
__global__ __launch_bounds__(256)
void hh_wprep(const float* __restrict__ Wq, const float* __restrict__ Wk,
              const int* __restrict__ lidx, u16* __restrict__ WT)
{
  __shared__ float tile[64*65];
  int bid = blockIdx.x, which = bid & 1, h = bid >> 1;
  const float* Wsrc = (which ? Wk : Wq) + (size_t)(*lidx)*(H_N*D_N*F_N) + (size_t)h*(D_N*F_N);
  u16* dh = WT + which*(2*WT_MAT) + h*WT_HEAD;
  u16* dl = dh + WT_MAT;
  int t = threadIdx.x;
  #pragma unroll
  for (int i=0;i<16;++i){
    int idx = i*256 + t;                      // idx = d*64 + f
    tile[(idx&63)*65 + (idx>>6)] = Wsrc[idx]; // tile[f][d]
  }
  __syncthreads();
  #pragma unroll
  for (int i=0;i<16;++i){
    int idx = i*256 + t;                      // idx = f*64 + d
    float w = tile[(idx>>6)*65 + (idx&63)];
    u16 hh,ll; split_hl(w,hh,ll);
    dh[idx] = hh; dl[idx] = ll;
  }
}

// ---------------- Phase 1: per-chunk S_t = phi_k^T v (MFMA), z_t ------------
// LDS = 34 KB -> 4 blocks/CU so the whole 1024-block grid is co-resident.
__global__ __launch_bounds__(256,4)
void hh_chunksums(const float* __restrict__ kin, const float* __restrict__ vin,
                  const u16* __restrict__ WkT,
                  u16* __restrict__ Sh_ws, u16* __restrict__ Sl_ws,
                  float* __restrict__ z_ws)
{
  __shared__ __align__(16) char sm[34816];
  u16*  pkT_h = (u16*)sm;               // [128 f][64 r] bf16 hi (16 KB)
  u16*  pkT_l = (u16*)(sm + 16384);
  float* zb   = (float*)(sm + 32768);   // [4][128] partial z (2 KB)

  int bid = blockIdx.x, bh = bid>>5, c = bid & (NC_N-1), h = bh & (H_N-1);
  const float* Xk = kin + ((size_t)bh*L_N + c*CH_N)*D_N;
  const float* Vc = vin + ((size_t)bh*L_N + c*CH_N)*D_N;
  const u16* Wh = WkT + h*WT_HEAD;
  const u16* Wl = Wh + WT_MAT;
  int t = threadIdx.x, lane = t&63, w = t>>6;
  int m0 = w*16, lrow = lane&15, k0l = (lane>>4)*8;

  // V^T A-frag loads early (column reads; latency hidden under phi gen)
  float vcol[16];
  #pragma unroll
  for (int ks=0; ks<2; ++ks)
    #pragma unroll
    for (int j=0; j<8; ++j)
      vcol[ks*8+j] = Vc[(size_t)(ks*32 + k0l + j)*D_N + m0 + lrow];

  f32x4 oacc[4], pP[4], pM[4];
  o_mfma(Xk, Wh, Wl, m0, lane, oacc);
  softmax_cl(oacc, pP, pM);
  store_phi_tr(pkT_h, pkT_l, m0, lane, pP, pM);

  // z column sums (over this wave's 16 rows, then cross-lkg shuffle)
  #pragma unroll
  for (int ft=0; ft<4; ++ft){
    float sP = pP[ft][0]+pP[ft][1]+pP[ft][2]+pP[ft][3];
    float sM = pM[ft][0]+pM[ft][1]+pM[ft][2]+pM[ft][3];
    sP += __shfl_xor(sP,16,64); sP += __shfl_xor(sP,32,64);
    sM += __shfl_xor(sM,16,64); sM += __shfl_xor(sM,32,64);
    if ((lane>>4)==0){
      zb[w*128 + ft*16 + lane]      = sP;
      zb[w*128 + 64 + ft*16 + lane] = sM;
    }
  }
  __syncthreads();

  if (t < FF_N)
    z_ws[(size_t)(bh*NC_N + c)*FF_N + t] = zb[t] + zb[128+t] + zb[256+t] + zb[384+t];

  // A-frags from the early V column loads
  bf16x8 ah[2], al[2];
  #pragma unroll
  for (int ks=0; ks<2; ++ks)
    #pragma unroll
    for (int j=0; j<8; ++j){
      u16 hh,ll; split_hl(vcol[ks*8+j],hh,ll);
      ah[ks][j]=(short)hh; al[ks][j]=(short)ll;
    }

  // S[d][f] = sum_r V^T[d][r] * phik[r][f]; wave w owns d-tile w.
  f32x4 acc[8];
  #pragma unroll
  for (int ft=0; ft<8; ++ft) acc[ft] = (f32x4){0.f,0.f,0.f,0.f};
  #pragma unroll
  for (int ks=0; ks<2; ++ks){
    int r0k = ks*32 + k0l;
    #pragma unroll
    for (int ft=0; ft<8; ++ft){
      bf16x8 bh = ldf64(pkT_h, ft*16 + lrow, r0k);
      bf16x8 bl = ldf64(pkT_l, ft*16 + lrow, r0k);
      acc[ft] = MFMA16(ah[ks], bh, acc[ft]);
      acc[ft] = MFMA16(ah[ks], bl, acc[ft]);
      acc[ft] = MFMA16(al[ks], bh, acc[ft]);
    }
  }
  // S out as bf16 hi/lo planes (aggregate per chunk; scan turns into prefix)
  u16* Shout = Sh_ws + (size_t)(bh*NC_N + c)*S_STRIDE;
  u16* Slout = Sl_ws + (size_t)(bh*NC_N + c)*S_STRIDE;
  #pragma unroll
  for (int ft=0; ft<8; ++ft)
    #pragma unroll
    for (int reg=0; reg<4; ++reg){
      int d = m0 + (lane>>4)*4 + reg;
      int idx = d*FF_N + ft*16 + lrow;
      u16 hh,ll; split_hl(acc[ft][reg],hh,ll);
      Shout[idx] = hh; Slout[idx] = ll;
    }
}

// ---------------- Phase 2: exclusive prefix scan over chunks (bf16 planes) --
__global__ __launch_bounds__(256)
void hh_scan(u16* __restrict__ Sh_ws, u16* __restrict__ Sl_ws,
             float* __restrict__ z_ws)
{
  int bid = blockIdx.x;
  int bh = bid / 17, s = bid % 17;
  int t = threadIdx.x;
  if (s < 16){
    // 2 elements per thread via paired u32 plane loads
    size_t base = (size_t)bh*NC_N*S_STRIDE + (size_t)s*512 + 2*t;
    float run0 = 0.f, run1 = 0.f;
    u32 nh = *reinterpret_cast<const u32*>(Sh_ws + base);
    u32 nl = *reinterpret_cast<const u32*>(Sl_ws + base);
    #pragma unroll
    for (int c=0; c<NC_N; ++c){
      u32 ch = nh, cl = nl;
      if (c+1 < NC_N){
        nh = *reinterpret_cast<const u32*>(Sh_ws + base + (size_t)(c+1)*S_STRIDE);
        nl = *reinterpret_cast<const u32*>(Sl_ws + base + (size_t)(c+1)*S_STRIDE);
      }
      // write exclusive prefix (run) over the aggregate slot
      u16 h0,l0,h1,l1; split_hl(run0,h0,l0); split_hl(run1,h1,l1);
      *reinterpret_cast<u32*>(Sh_ws + base + (size_t)c*S_STRIDE) = (u32)h0 | ((u32)h1<<16);
      *reinterpret_cast<u32*>(Sl_ws + base + (size_t)c*S_STRIDE) = (u32)l0 | ((u32)l1<<16);
      // accumulate reconstructed aggregate (hi+lo add is exact in fp32)
      run0 += __uint_as_float((ch & 0xffffu) << 16) + __uint_as_float((cl & 0xffffu) << 16);
      run1 += __uint_as_float(ch & 0xffff0000u)     + __uint_as_float(cl & 0xffff0000u);
    }
  } else if (t < FF_N){
    size_t base = (size_t)bh*NC_N*FF_N + t;
    float run = 0.f;
    float nxt = z_ws[base];
    #pragma unroll
    for (int c=0;c<NC_N;++c){
      float cur = nxt;
      if (c+1 < NC_N) nxt = z_ws[base + (size_t)(c+1)*FF_N];
      z_ws[base + (size_t)c*FF_N] = run;
      run += cur;
    }
  }
}

// ---------------- Phase 3: per-chunk output (everything on MFMA) ------------
// Round-4 schedule (numer interleaved with A-GEMM after the barrier), with
// S-prefix B-frags loaded directly from bf16 planes (no cvt).
__global__ __launch_bounds__(256,4)
void hh_output(const float* __restrict__ qin, const float* __restrict__ kin,
               const float* __restrict__ vin,
               const u16* __restrict__ WT,   // [WqT_h|WqT_l|WkT_h|WkT_l]
               const u16* __restrict__ Sh_ws, const u16* __restrict__ Sl_ws,
               const float* __restrict__ z_ws,
               float* __restrict__ out)
{
  __shared__ __align__(16) char sm[32768];
  u16*  ph   = (u16*)sm;                // phi tile hi [64][128] swz (16 KB)
  u16*  pl   = (u16*)(sm + 16384);      // lo
  float* aA  = (float*)sm;              // A [64][64] fp32 — aliases ph
  u16*  vt_h = (u16*)(sm + 16384);      // V^T — aliases pl
  u16*  vt_l = (u16*)(sm + 24576);

  int bid = blockIdx.x, bh = bid>>5, c = bid & (NC_N-1), h = bh & (H_N-1);
  const float* Xq = qin + ((size_t)bh*L_N + c*CH_N)*D_N;
  const float* Xk = kin + ((size_t)bh*L_N + c*CH_N)*D_N;
  const float* Vc = vin + ((size_t)bh*L_N + c*CH_N)*D_N;
  const u16* Sph = Sh_ws + (size_t)(bh*NC_N + c)*S_STRIDE; // excl prefix [d][2F] hi
  const u16* Spl = Sl_ws + (size_t)(bh*NC_N + c)*S_STRIDE; // lo
  const float* zp = z_ws + (size_t)(bh*NC_N + c)*FF_N;
  const u16* WqTh = WT + h*WT_HEAD;
  const u16* WqTl = WqTh + WT_MAT;
  const u16* WkTh = WT + 2*WT_MAT + h*WT_HEAD;
  const u16* WkTl = WkTh + WT_MAT;
  int t = threadIdx.x, lane = t&63, w = t>>6;
  int m0 = w*16, lrow = lane&15, lkg = lane>>4, k0l = lkg*8;

  // ---- phi_q: einsum (MFMA) + softmax + dz, through own-rows LDS to A-frags
  f32x4 oacc[4], pP[4], pM[4];
  o_mfma(Xq, WqTh, WqTl, m0, lane, oacc);
  softmax_cl(oacc, pP, pM);

  float dz[4];
  {
    float zqP[4], zqM[4];
    #pragma unroll
    for (int ft=0; ft<4; ++ft){
      zqP[ft] = zp[ft*16 + lrow];
      zqM[ft] = zp[64 + ft*16 + lrow];
    }
    #pragma unroll
    for (int reg=0; reg<4; ++reg){
      float s = 0.f;
      #pragma unroll
      for (int ft=0; ft<4; ++ft)
        s += pP[ft][reg]*zqP[ft] + pM[ft][reg]*zqM[ft];
      #pragma unroll
      for (int o=8;o>0;o>>=1) s += __shfl_xor(s,o,64);
      dz[reg] = s;
    }
  }

  store_phi_rm(ph, pl, m0, lane, pP, pM);
  // Each wave reads only its own 16 rows (which only it wrote) -> no barrier.
  bf16x8 qh[4], ql[4];
  #pragma unroll
  for (int ks=0; ks<4; ++ks){
    qh[ks] = ldf128(ph, m0 + lrow, ks*32 + k0l);
    ql[ks] = ldf128(pl, m0 + lrow, ks*32 + k0l);
  }

  // ---- phi_k into the same tile (own rows again; no barrier needed yet)
  o_mfma(Xk, WkTh, WkTl, m0, lane, oacc);
  softmax_cl(oacc, pP, pM);
  store_phi_rm(ph, pl, m0, lane, pP, pM);

  // V loads (latency hidden under the MFMA section below)
  int vn = t>>2, vd0 = (t&3)*16;
  float4 vreg[4];
  #pragma unroll
  for (int p=0;p<4;++p)
    vreg[p] = *reinterpret_cast<const float4*>(Vc + (size_t)vn*D_N + vd0 + p*4);

  __syncthreads();  // all phi_k rows visible to all waves

  f32x4 accA[4], accO[4];
  #pragma unroll
  for (int i=0;i<4;++i){ accA[i]=(f32x4){0,0,0,0}; accO[i]=(f32x4){0,0,0,0}; }

  #pragma unroll
  for (int ks=0; ks<4; ++ks){
    int f0 = ks*32 + k0l;
    // intra A = phiq . phik^T (only ntiles <= w)
    #pragma unroll
    for (int nt=0; nt<4; ++nt){
      if (nt <= w){
        bf16x8 kh = ldf128(ph, nt*16 + lrow, f0);
        bf16x8 kl = ldf128(pl, nt*16 + lrow, f0);
        accA[nt] = MFMA16(qh[ks], kh, accA[nt]);
        accA[nt] = MFMA16(qh[ks], kl, accA[nt]);
        accA[nt] = MFMA16(ql[ks], kh, accA[nt]);
      }
    }
    // inter numer = phiq . S_prefix^T (B-frags straight from bf16 planes)
    #pragma unroll
    for (int dt=0; dt<4; ++dt){
      bf16x8 sh = *reinterpret_cast<const bf16x8*>(Sph + (size_t)(dt*16 + lrow)*FF_N + f0);
      bf16x8 sl = *reinterpret_cast<const bf16x8*>(Spl + (size_t)(dt*16 + lrow)*FF_N + f0);
      accO[dt] = MFMA16(qh[ks], sh, accO[dt]);
      accO[dt] = MFMA16(qh[ks], sl, accO[dt]);
      accO[dt] = MFMA16(ql[ks], sh, accO[dt]);
    }
  }

  // causal mask own tile, row-sum for denominator
  float rs[4] = {0.f,0.f,0.f,0.f};
  #pragma unroll
  for (int nt=0; nt<4; ++nt)
    #pragma unroll
    for (int reg=0; reg<4; ++reg){
      float a = accA[nt][reg];
      if (nt > w) a = 0.f;
      if (nt == w && lrow > lkg*4 + reg) a = 0.f;  // keep n <= m
      accA[nt][reg] = a;
      rs[reg] += a;
    }
  float den[4];
  #pragma unroll
  for (int reg=0; reg<4; ++reg){
    float s = rs[reg];
    s += __shfl_xor(s,1,64); s += __shfl_xor(s,2,64);
    s += __shfl_xor(s,4,64); s += __shfl_xor(s,8,64);
    den[reg] = dz[reg] + s + EPSF;
  }

  __syncthreads();   // all waves done reading phik tile; safe to alias

  #pragma unroll
  for (int nt=0; nt<4; ++nt)
    #pragma unroll
    for (int reg=0; reg<4; ++reg){
      int m = m0 + lkg*4 + reg;
      aA[ixA(m, nt*16 + lrow)] = accA[nt][reg];
    }
  #pragma unroll
  for (int p=0;p<4;++p){
    float vals[4] = {vreg[p].x, vreg[p].y, vreg[p].z, vreg[p].w};
    #pragma unroll
    for (int e=0;e<4;++e){
      int d = vd0 + p*4 + e;
      u16 hh,ll; split_hl(vals[e],hh,ll);
      vt_h[ix64(d, vn)] = hh;
      vt_l[ix64(d, vn)] = ll;
    }
  }
  __syncthreads();

  // PV: accO += A . V   (waves 0,1 need 1 kstep; waves 2,3 need 2)
  #pragma unroll
  for (int ks=0; ks<2; ++ks){
    if (ks <= (w>>1)){
      int n0 = ks*32 + k0l;
      int m  = m0 + lrow;
      f32x4 a0 = *reinterpret_cast<const f32x4*>(aA + ixA(m, n0));
      f32x4 a1 = *reinterpret_cast<const f32x4*>(aA + ixA(m, n0+4));
      float av[8] = {a0[0],a0[1],a0[2],a0[3],a1[0],a1[1],a1[2],a1[3]};
      bf16x8 Ah, Al;
      #pragma unroll
      for (int i=0;i<8;++i){ u16 hh,ll; split_hl(av[i],hh,ll); Ah[i]=(short)hh; Al[i]=(short)ll; }
      #pragma unroll
      for (int dt=0; dt<4; ++dt){
        bf16x8 vh = ldf64(vt_h, dt*16 + lrow, n0);
        bf16x8 vl = ldf64(vt_l, dt*16 + lrow, n0);
        accO[dt] = MFMA16(Ah, vh, accO[dt]);
        accO[dt] = MFMA16(Ah, vl, accO[dt]);
        accO[dt] = MFMA16(Al, vh, accO[dt]);
      }
    }
  }

  #pragma unroll
  for (int reg=0; reg<4; ++reg){
    float inv = 1.0f / den[reg];
    int m = m0 + lkg*4 + reg;
    float* orow = out + ((size_t)bh*L_N + c*CH_N + m)*D_N;
    #pragma unroll
    for (int dt=0; dt<4; ++dt)
      orow[dt*16 + lrow] = accO[dt][reg] * inv;
  }
}

extern "C" void kernel_launch(void* const* d_in, const int* in_sizes, int n_in,
                              void* d_out, int out_size, void* d_ws, size_t ws_size,
                              hipStream_t stream) {
  const float* q    = (const float*)d_in[0];
  const float* k    = (const float*)d_in[1];
  const float* v    = (const float*)d_in[2];
  const float* Wq   = (const float*)d_in[3];
  const float* Wk   = (const float*)d_in[4];
  const int*   lidx = (const int*)d_in[5];
  float* out  = (float*)d_out;
  u16*   Sh_ws = (u16*)d_ws;                          // 16.78 MB
  u16*   Sl_ws = Sh_ws + SH_TOTAL;                    // 16.78 MB
  float* z_ws  = (float*)(Sl_ws + SH_TOTAL);          // 0.52 MB
  u16*   WT    = (u16*)(z_ws + Z_TOTAL);              // 0.5 MB

  hh_wprep    <<<2*H_N,     256, 0, stream>>>(Wq, Wk, lidx, WT);
  hh_chunksums<<<BH_N*NC_N, 256, 0, stream>>>(k, v, WT + 2*WT_MAT, Sh_ws, Sl_ws, z_ws);
  hh_scan     <<<BH_N*17,   256, 0, stream>>>(Sh_ws, Sl_ws, z_ws);
  hh_output   <<<BH_N*NC_N, 256, 0, stream>>>(q, k, v, WT, Sh_ws, Sl_ws, z_ws, out);
}